// Round 1
// baseline (1647.656 us; speedup 1.0000x reference)
//
#include <hip/hip_runtime.h>

#define N_NODES 100000
#define N_EDGES 3200000
#define N_GRAPHS 1000
#define NLAYER 4

// ---------------------------------------------------------------------------
// h[v][c] = sum_k x[v][k]*emb_w[k][c] + emb_b[c]
__global__ __launch_bounds__(256) void embed_kernel(
    const float* __restrict__ x, const float* __restrict__ emb_w,
    const float* __restrict__ emb_b, float* __restrict__ h)
{
  int t = blockIdx.x * 256 + threadIdx.x;
  if (t >= N_NODES * 64) return;
  int c = t & 63, v = t >> 6;
  float acc = emb_b[c];
#pragma unroll
  for (int k = 0; k < 4; ++k) acc = fmaf(x[v * 4 + k], emb_w[k * 64 + c], acc);
  h[t] = acc;
}

// ---------------------------------------------------------------------------
// per-dst in-degree count + weighted degree sum
__global__ __launch_bounds__(256) void hist_kernel(
    const int* __restrict__ ei, const float* __restrict__ ea,
    int* __restrict__ cnt, float* __restrict__ degw)
{
  int e = blockIdx.x * 256 + threadIdx.x;
  if (e >= N_EDGES) return;
  int d = ei[N_EDGES + e];
  atomicAdd(&cnt[d], 1);
  atomicAdd(&degw[d], ea[e]);
}

// block-local exclusive scan (256/block) + block sums
__global__ __launch_bounds__(256) void scan1_kernel(
    const int* __restrict__ cnt, int* __restrict__ row_off, int* __restrict__ bsum)
{
  __shared__ int s[256];
  int i = blockIdx.x * 256 + threadIdx.x;
  int x = (i < N_NODES) ? cnt[i] : 0;
  s[threadIdx.x] = x;
  __syncthreads();
  for (int off = 1; off < 256; off <<= 1) {
    int y = (threadIdx.x >= off) ? s[threadIdx.x - off] : 0;
    __syncthreads();
    s[threadIdx.x] += y;
    __syncthreads();
  }
  if (i < N_NODES) row_off[i] = s[threadIdx.x] - x;
  if (threadIdx.x == 255) bsum[blockIdx.x] = s[255];
}

__global__ __launch_bounds__(512) void scan2_kernel(
    const int* __restrict__ bsum, int* __restrict__ bpre, int nb)
{
  __shared__ int s[512];
  int x = ((int)threadIdx.x < nb) ? bsum[threadIdx.x] : 0;
  s[threadIdx.x] = x;
  __syncthreads();
  for (int off = 1; off < 512; off <<= 1) {
    int y = (threadIdx.x >= off) ? s[threadIdx.x - off] : 0;
    __syncthreads();
    s[threadIdx.x] += y;
    __syncthreads();
  }
  bpre[threadIdx.x] = s[threadIdx.x] - x;
}

__global__ __launch_bounds__(256) void scan3_kernel(
    int* __restrict__ row_off, const int* __restrict__ bpre, int* __restrict__ cursor)
{
  int i = blockIdx.x * 256 + threadIdx.x;
  if (i < N_NODES) {
    int r = row_off[i] + bpre[i >> 8];
    row_off[i] = r;
    cursor[i] = r;
  } else if (i == N_NODES) {
    row_off[N_NODES] = N_EDGES;
  }
}

// scatter edges into CSR-by-dst
__global__ __launch_bounds__(256) void scatter_kernel(
    const int* __restrict__ ei, const float* __restrict__ ea,
    int* __restrict__ cursor, int* __restrict__ csr_src, float* __restrict__ csr_ew)
{
  int e = blockIdx.x * 256 + threadIdx.x;
  if (e >= N_EDGES) return;
  int d = ei[N_EDGES + e];
  int pos = atomicAdd(&cursor[d], 1);
  csr_src[pos] = ei[e];
  csr_ew[pos] = ea[e];
}

// ---------------------------------------------------------------------------
// fused 3-matvec per node:
//   a_out  = h@W1 + b1
//   cc_out = (h@W3 + b3) - deg_w * (h@W2)
__device__ __forceinline__ void fma4(float4& a, float s, const float4& w) {
  a.x = fmaf(s, w.x, a.x);
  a.y = fmaf(s, w.y, a.y);
  a.z = fmaf(s, w.z, a.z);
  a.w = fmaf(s, w.w, a.w);
}

__global__ __launch_bounds__(256) void matvec3_kernel(
    const float* __restrict__ h,
    const float* __restrict__ w1, const float* __restrict__ b1,
    const float* __restrict__ w2,
    const float* __restrict__ w3, const float* __restrict__ b3,
    const float* __restrict__ degw,
    float* __restrict__ a_out, float* __restrict__ cc_out)
{
  // ws layout: [0..1023]=W2, [1024..2047]=W1, [2048..3071]=W3 (float4 granules)
  __shared__ float4 ws[3 * 1024];
  __shared__ float b1s[64], b3s[64];
  int tid = threadIdx.x;
  const float4* w1v = (const float4*)w1;
  const float4* w2v = (const float4*)w2;
  const float4* w3v = (const float4*)w3;
  for (int i = tid; i < 1024; i += 256) {
    ws[i] = w2v[i];
    ws[1024 + i] = w1v[i];
    ws[2048 + i] = w3v[i];
  }
  if (tid < 64) { b1s[tid] = b1[tid]; b3s[tid] = b3[tid]; }
  __syncthreads();

  int v = blockIdx.x * 256 + tid;
  if (v >= N_NODES) return;
  const float4* hp = (const float4*)(h + (size_t)v * 64);
  float4* ap = (float4*)(a_out + (size_t)v * 64);
  float4* ccp = (float4*)(cc_out + (size_t)v * 64);
  float dw = degw[v];
  float4 acc[16];

  // ---- W2: cc = b3 - dw*(h@W2) ----
#pragma unroll
  for (int j = 0; j < 16; ++j) acc[j] = make_float4(0.f, 0.f, 0.f, 0.f);
#pragma unroll 4
  for (int k4 = 0; k4 < 16; ++k4) {
    float4 hk = hp[k4];
    const float4* wr = &ws[k4 * 64];
#pragma unroll
    for (int j = 0; j < 16; ++j) {
      fma4(acc[j], hk.x, wr[j]);
      fma4(acc[j], hk.y, wr[16 + j]);
      fma4(acc[j], hk.z, wr[32 + j]);
      fma4(acc[j], hk.w, wr[48 + j]);
    }
  }
#pragma unroll
  for (int j = 0; j < 16; ++j) {
    float4 t;
    t.x = b3s[4 * j + 0] - dw * acc[j].x;
    t.y = b3s[4 * j + 1] - dw * acc[j].y;
    t.z = b3s[4 * j + 2] - dw * acc[j].z;
    t.w = b3s[4 * j + 3] - dw * acc[j].w;
    ccp[j] = t;
  }

  // ---- W1: a = h@W1 + b1 ----
#pragma unroll
  for (int j = 0; j < 16; ++j)
    acc[j] = make_float4(b1s[4 * j + 0], b1s[4 * j + 1], b1s[4 * j + 2], b1s[4 * j + 3]);
#pragma unroll 4
  for (int k4 = 0; k4 < 16; ++k4) {
    float4 hk = hp[k4];
    const float4* wr = &ws[1024 + k4 * 64];
#pragma unroll
    for (int j = 0; j < 16; ++j) {
      fma4(acc[j], hk.x, wr[j]);
      fma4(acc[j], hk.y, wr[16 + j]);
      fma4(acc[j], hk.z, wr[32 + j]);
      fma4(acc[j], hk.w, wr[48 + j]);
    }
  }
#pragma unroll
  for (int j = 0; j < 16; ++j) ap[j] = acc[j];

  // ---- W3: cc += h@W3 ----
#pragma unroll
  for (int j = 0; j < 16; ++j) acc[j] = make_float4(0.f, 0.f, 0.f, 0.f);
#pragma unroll 4
  for (int k4 = 0; k4 < 16; ++k4) {
    float4 hk = hp[k4];
    const float4* wr = &ws[2048 + k4 * 64];
#pragma unroll
    for (int j = 0; j < 16; ++j) {
      fma4(acc[j], hk.x, wr[j]);
      fma4(acc[j], hk.y, wr[16 + j]);
      fma4(acc[j], hk.z, wr[32 + j]);
      fma4(acc[j], hk.w, wr[48 + j]);
    }
  }
#pragma unroll
  for (int j = 0; j < 16; ++j) {
    float4 t = ccp[j];
    t.x += acc[j].x; t.y += acc[j].y; t.z += acc[j].z; t.w += acc[j].w;
    ccp[j] = t;
  }
}

// ---------------------------------------------------------------------------
// h_new[v] = relu(cc[v] + sum_{e in CSR(v)} ew_e * a[src_e])   (wave per node)
__global__ __launch_bounds__(256) void agg_kernel(
    const float* __restrict__ a, const float* __restrict__ cc,
    const int* __restrict__ row_off, const int* __restrict__ csr_src,
    const float* __restrict__ csr_ew, float* __restrict__ h)
{
  int wid = (blockIdx.x * 256 + threadIdx.x) >> 6;
  int lane = threadIdx.x & 63;
  if (wid >= N_NODES) return;
  int base = row_off[wid];
  int ecnt = row_off[wid + 1] - base;
  float acc = cc[(size_t)wid * 64 + lane];
  for (int c0 = 0; c0 < ecnt; c0 += 64) {
    int take = min(ecnt - c0, 64);
    int ms = 0;
    float mw = 0.f;
    if (lane < take) {
      ms = csr_src[base + c0 + lane];
      mw = csr_ew[base + c0 + lane];
    }
    for (int j = 0; j < take; ++j) {
      int s = __shfl(ms, j);
      float w = __shfl(mw, j);
      acc = fmaf(w, a[(size_t)s * 64 + lane], acc);
    }
  }
  h[(size_t)wid * 64 + lane] = fmaxf(acc, 0.f);
}

// ---------------------------------------------------------------------------
// fused mean-pool (sorted batch, binary search) + lin1+relu + lin2, wave/graph
__global__ __launch_bounds__(256) void head_kernel(
    const float* __restrict__ h, const int* __restrict__ batch,
    const float* __restrict__ l1w, const float* __restrict__ l1b,
    const float* __restrict__ l2w, const float* __restrict__ l2b,
    float* __restrict__ out)
{
  int g = (blockIdx.x * 256 + threadIdx.x) >> 6;
  int lane = threadIdx.x & 63;
  if (g >= N_GRAPHS) return;
  int lo = 0, hi = N_NODES;
  while (lo < hi) { int mid = (lo + hi) >> 1; if (batch[mid] < g) lo = mid + 1; else hi = mid; }
  int start = lo;
  hi = N_NODES;
  while (lo < hi) { int mid = (lo + hi) >> 1; if (batch[mid] < g + 1) lo = mid + 1; else hi = mid; }
  int end = lo;

  float sum = 0.f;
  for (int v = start; v < end; ++v) sum += h[(size_t)v * 64 + lane];
  float cntf = (float)(end - start);
  float gx = sum / fmaxf(cntf, 1.f);

  float acc = l1b[lane];
  for (int k = 0; k < 64; ++k) {
    float gxk = __shfl(gx, k);
    acc = fmaf(gxk, l1w[k * 64 + lane], acc);
  }
  float t = fmaxf(acc, 0.f);
  float p0 = t * l2w[lane * 3 + 0];
  float p1 = t * l2w[lane * 3 + 1];
  float p2 = t * l2w[lane * 3 + 2];
  for (int off = 32; off > 0; off >>= 1) {
    p0 += __shfl_down(p0, off);
    p1 += __shfl_down(p1, off);
    p2 += __shfl_down(p2, off);
  }
  if (lane == 0) {
    out[g * 3 + 0] = p0 + l2b[0];
    out[g * 3 + 1] = p1 + l2b[1];
    out[g * 3 + 2] = p2 + l2b[2];
  }
}

// ---------------------------------------------------------------------------
extern "C" void kernel_launch(void* const* d_in, const int* in_sizes, int n_in,
                              void* d_out, int out_size, void* d_ws, size_t ws_size,
                              hipStream_t stream)
{
  (void)in_sizes; (void)n_in; (void)out_size; (void)ws_size;
  const float* x     = (const float*)d_in[0];
  const int*   ei    = (const int*)d_in[1];
  const float* ea    = (const float*)d_in[2];
  const int*   batch = (const int*)d_in[3];
  const float* emb_w = (const float*)d_in[4];
  const float* emb_b = (const float*)d_in[5];
  const float* cw1   = (const float*)d_in[6];
  const float* cb1   = (const float*)d_in[7];
  const float* cw2   = (const float*)d_in[8];
  const float* cw3   = (const float*)d_in[9];
  const float* cb3   = (const float*)d_in[10];
  const float* l1w   = (const float*)d_in[11];
  const float* l1b   = (const float*)d_in[12];
  const float* l2w   = (const float*)d_in[13];
  const float* l2b   = (const float*)d_in[14];
  float* out = (float*)d_out;

  char* wsb = (char*)d_ws;
  size_t off = 0;
  auto alloc = [&](size_t bytes) {
    char* p = wsb + off;
    off = (off + bytes + 255) & ~(size_t)255;
    return p;
  };
  float* h       = (float*)alloc(sizeof(float) * (size_t)N_NODES * 64);
  float* a_buf   = (float*)alloc(sizeof(float) * (size_t)N_NODES * 64);
  float* cc_buf  = (float*)alloc(sizeof(float) * (size_t)N_NODES * 64);
  int*   csr_src = (int*)alloc(sizeof(int) * (size_t)N_EDGES);
  float* csr_ew  = (float*)alloc(sizeof(float) * (size_t)N_EDGES);
  int*   row_off = (int*)alloc(sizeof(int) * (N_NODES + 1));
  int*   cursor  = (int*)alloc(sizeof(int) * N_NODES);
  int*   cnt     = (int*)alloc(sizeof(int) * N_NODES);
  float* degw    = (float*)alloc(sizeof(float) * N_NODES);
  int*   bsum    = (int*)alloc(sizeof(int) * 512);
  int*   bpre    = (int*)alloc(sizeof(int) * 512);

  (void)hipMemsetAsync(cnt, 0, sizeof(int) * N_NODES, stream);
  (void)hipMemsetAsync(degw, 0, sizeof(float) * N_NODES, stream);

  embed_kernel<<<(N_NODES * 64 + 255) / 256, 256, 0, stream>>>(x, emb_w, emb_b, h);
  hist_kernel<<<(N_EDGES + 255) / 256, 256, 0, stream>>>(ei, ea, cnt, degw);
  int nb = (N_NODES + 255) / 256;  // 391
  scan1_kernel<<<nb, 256, 0, stream>>>(cnt, row_off, bsum);
  scan2_kernel<<<1, 512, 0, stream>>>(bsum, bpre, nb);
  scan3_kernel<<<(N_NODES + 1 + 255) / 256, 256, 0, stream>>>(row_off, bpre, cursor);
  scatter_kernel<<<(N_EDGES + 255) / 256, 256, 0, stream>>>(ei, ea, cursor, csr_src, csr_ew);

  for (int l = 0; l < NLAYER; ++l) {
    matvec3_kernel<<<nb, 256, 0, stream>>>(
        h, cw1 + l * 4096, cb1 + l * 64, cw2 + l * 4096, cw3 + l * 4096,
        cb3 + l * 64, degw, a_buf, cc_buf);
    agg_kernel<<<(N_NODES * 64 + 255) / 256, 256, 0, stream>>>(
        a_buf, cc_buf, row_off, csr_src, csr_ew, h);
  }

  head_kernel<<<(N_GRAPHS * 64 + 255) / 256, 256, 0, stream>>>(
      h, batch, l1w, l1b, l2w, l2b, out);
}

// Round 2
// 1116.194 us; speedup vs baseline: 1.4761x; 1.4761x over previous
//
#include <hip/hip_runtime.h>

#define N_NODES 100000
#define N_EDGES 3200000
#define N_GRAPHS 1000
#define NLAYER 4

// ---------------------------------------------------------------------------
// h[v][c] = sum_k x[v][k]*emb_w[k][c] + emb_b[c]
__global__ __launch_bounds__(256) void embed_kernel(
    const float* __restrict__ x, const float* __restrict__ emb_w,
    const float* __restrict__ emb_b, float* __restrict__ h)
{
  int t = blockIdx.x * 256 + threadIdx.x;
  if (t >= N_NODES * 64) return;
  int c = t & 63, v = t >> 6;
  float acc = emb_b[c];
#pragma unroll
  for (int k = 0; k < 4; ++k) acc = fmaf(x[v * 4 + k], emb_w[k * 64 + c], acc);
  h[t] = acc;
}

// ---------------------------------------------------------------------------
// ONE packed u64 atomic per edge: high32 = count, low32 = fixed-point sum(ew).
// Return value's high word = this edge's rank within its dst bucket.
__global__ __launch_bounds__(256) void hist_kernel(
    const int* __restrict__ ei, const float* __restrict__ ea,
    unsigned long long* __restrict__ packed, int* __restrict__ rank)
{
  int e = blockIdx.x * 256 + threadIdx.x;
  if (e >= N_EDGES) return;
  int d = ei[N_EDGES + e];
  unsigned q = (unsigned)(ea[e] * 8388608.0f + 0.5f);  // ew * 2^23, ew in [0,1)
  unsigned long long old =
      atomicAdd(&packed[d], (1ULL << 32) | (unsigned long long)q);
  rank[e] = (int)(old >> 32);
}

// block-local exclusive scan (256/block) + block sums; input = packed high word
__global__ __launch_bounds__(256) void scan1_kernel(
    const unsigned long long* __restrict__ packed,
    int* __restrict__ row_off, int* __restrict__ bsum)
{
  __shared__ int s[256];
  int i = blockIdx.x * 256 + threadIdx.x;
  int x = (i < N_NODES) ? (int)(packed[i] >> 32) : 0;
  s[threadIdx.x] = x;
  __syncthreads();
  for (int off = 1; off < 256; off <<= 1) {
    int y = (threadIdx.x >= off) ? s[threadIdx.x - off] : 0;
    __syncthreads();
    s[threadIdx.x] += y;
    __syncthreads();
  }
  if (i < N_NODES) row_off[i] = s[threadIdx.x] - x;
  if (threadIdx.x == 255) bsum[blockIdx.x] = s[255];
}

__global__ __launch_bounds__(512) void scan2_kernel(
    const int* __restrict__ bsum, int* __restrict__ bpre, int nb)
{
  __shared__ int s[512];
  int x = ((int)threadIdx.x < nb) ? bsum[threadIdx.x] : 0;
  s[threadIdx.x] = x;
  __syncthreads();
  for (int off = 1; off < 512; off <<= 1) {
    int y = (threadIdx.x >= off) ? s[threadIdx.x - off] : 0;
    __syncthreads();
    s[threadIdx.x] += y;
    __syncthreads();
  }
  bpre[threadIdx.x] = s[threadIdx.x] - x;
}

// finalize row_off; also unpack degw from packed low word
__global__ __launch_bounds__(256) void scan3_kernel(
    int* __restrict__ row_off, const int* __restrict__ bpre,
    const unsigned long long* __restrict__ packed, float* __restrict__ degw)
{
  int i = blockIdx.x * 256 + threadIdx.x;
  if (i < N_NODES) {
    row_off[i] += bpre[i >> 8];
    degw[i] = (float)(unsigned)(packed[i] & 0xffffffffu) * (1.0f / 8388608.0f);
  } else if (i == N_NODES) {
    row_off[N_NODES] = N_EDGES;
  }
}

// atomic-free scatter: pos = row_off[dst] + rank[e]; one 8B store per edge
__global__ __launch_bounds__(256) void scatter_kernel(
    const int* __restrict__ ei, const float* __restrict__ ea,
    const int* __restrict__ row_off, const int* __restrict__ rank,
    int2* __restrict__ csr)
{
  int e = blockIdx.x * 256 + threadIdx.x;
  if (e >= N_EDGES) return;
  int d = ei[N_EDGES + e];
  int pos = row_off[d] + rank[e];
  csr[pos] = make_int2(ei[e], __float_as_int(ea[e]));
}

// ---------------------------------------------------------------------------
// fused 3-matvec, 2 nodes per thread:
//   a_out  = h@W1 + b1
//   cc_out = b3 + h@W3 - deg_w * (h@W2)   (single accumulator: W2, *=-dw, +=W3)
__device__ __forceinline__ void fma4(float4& a, float s, const float4& w) {
  a.x = fmaf(s, w.x, a.x);
  a.y = fmaf(s, w.y, a.y);
  a.z = fmaf(s, w.z, a.z);
  a.w = fmaf(s, w.w, a.w);
}

__global__ __launch_bounds__(256) void matvec3_kernel(
    const float* __restrict__ h,
    const float* __restrict__ w1, const float* __restrict__ b1,
    const float* __restrict__ w2,
    const float* __restrict__ w3, const float* __restrict__ b3,
    const float* __restrict__ degw,
    float* __restrict__ a_out, float* __restrict__ cc_out)
{
  // LDS: [0..1023]=W2, [1024..2047]=W3, [2048..3071]=W1 (float4 granules)
  __shared__ float4 ws[3 * 1024];
  __shared__ float b1s[64], b3s[64];
  int tid = threadIdx.x;
  const float4* w1v = (const float4*)w1;
  const float4* w2v = (const float4*)w2;
  const float4* w3v = (const float4*)w3;
  for (int i = tid; i < 1024; i += 256) {
    ws[i] = w2v[i];
    ws[1024 + i] = w3v[i];
    ws[2048 + i] = w1v[i];
  }
  if (tid < 64) { b1s[tid] = b1[tid]; b3s[tid] = b3[tid]; }
  __syncthreads();

  int v0 = blockIdx.x * 512 + tid;
  int v1 = v0 + 256;
  bool val0 = v0 < N_NODES, val1 = v1 < N_NODES;
  int v0c = val0 ? v0 : 0;
  int v1c = val1 ? v1 : 0;
  const float4* hp0 = (const float4*)(h + (size_t)v0c * 64);
  const float4* hp1 = (const float4*)(h + (size_t)v1c * 64);
  float dw0 = degw[v0c], dw1 = degw[v1c];
  float4 acc0[16], acc1[16];

  auto mac_loop = [&](const float4* wbase) {
#pragma unroll 2
    for (int k4 = 0; k4 < 16; ++k4) {
      float4 hk0 = hp0[k4];
      float4 hk1 = hp1[k4];
      const float4* wr = wbase + k4 * 64;
#pragma unroll
      for (int j = 0; j < 16; ++j) {
        float4 wa = wr[j], wb = wr[16 + j], wc = wr[32 + j], wd = wr[48 + j];
        fma4(acc0[j], hk0.x, wa); fma4(acc0[j], hk0.y, wb);
        fma4(acc0[j], hk0.z, wc); fma4(acc0[j], hk0.w, wd);
        fma4(acc1[j], hk1.x, wa); fma4(acc1[j], hk1.y, wb);
        fma4(acc1[j], hk1.z, wc); fma4(acc1[j], hk1.w, wd);
      }
    }
  };

  // ---- cc phase: acc = h@W2; acc *= -dw; acc += h@W3; acc += b3 ----
#pragma unroll
  for (int j = 0; j < 16; ++j) {
    acc0[j] = make_float4(0.f, 0.f, 0.f, 0.f);
    acc1[j] = make_float4(0.f, 0.f, 0.f, 0.f);
  }
  mac_loop(&ws[0]);
#pragma unroll
  for (int j = 0; j < 16; ++j) {
    acc0[j].x *= -dw0; acc0[j].y *= -dw0; acc0[j].z *= -dw0; acc0[j].w *= -dw0;
    acc1[j].x *= -dw1; acc1[j].y *= -dw1; acc1[j].z *= -dw1; acc1[j].w *= -dw1;
  }
  mac_loop(&ws[1024]);
  {
    float4* ccp0 = (float4*)(cc_out + (size_t)v0c * 64);
    float4* ccp1 = (float4*)(cc_out + (size_t)v1c * 64);
#pragma unroll
    for (int j = 0; j < 16; ++j) {
      float4 bb = make_float4(b3s[4 * j], b3s[4 * j + 1], b3s[4 * j + 2], b3s[4 * j + 3]);
      if (val0) {
        float4 t = acc0[j];
        t.x += bb.x; t.y += bb.y; t.z += bb.z; t.w += bb.w;
        ccp0[j] = t;
      }
      if (val1) {
        float4 t = acc1[j];
        t.x += bb.x; t.y += bb.y; t.z += bb.z; t.w += bb.w;
        ccp1[j] = t;
      }
    }
  }

  // ---- a phase: acc = b1 + h@W1 ----
#pragma unroll
  for (int j = 0; j < 16; ++j) {
    float4 bb = make_float4(b1s[4 * j], b1s[4 * j + 1], b1s[4 * j + 2], b1s[4 * j + 3]);
    acc0[j] = bb;
    acc1[j] = bb;
  }
  mac_loop(&ws[2048]);
  {
    float4* ap0 = (float4*)(a_out + (size_t)v0c * 64);
    float4* ap1 = (float4*)(a_out + (size_t)v1c * 64);
#pragma unroll
    for (int j = 0; j < 16; ++j) {
      if (val0) ap0[j] = acc0[j];
      if (val1) ap1[j] = acc1[j];
    }
  }
}

// ---------------------------------------------------------------------------
// h_new[v] = relu(cc[v] + sum_{e in CSR(v)} ew_e * a[src_e])   (wave per node)
// CSR row is wave-uniform -> scalarize base so edge records go via scalar loads.
__global__ __launch_bounds__(256) void agg_kernel(
    const float* __restrict__ a, const float* __restrict__ cc,
    const int* __restrict__ row_off, const int2* __restrict__ csr,
    float* __restrict__ h)
{
  int wid = (blockIdx.x * 256 + threadIdx.x) >> 6;
  wid = __builtin_amdgcn_readfirstlane(wid);
  int lane = threadIdx.x & 63;
  if (wid >= N_NODES) return;
  int base = row_off[wid];
  int ecnt = row_off[wid + 1] - base;
  const int2* ep = csr + base;
  float acc = cc[(size_t)wid * 64 + lane];
  int j = 0;
  for (; j + 4 <= ecnt; j += 4) {
    int2 e0 = ep[j], e1 = ep[j + 1], e2 = ep[j + 2], e3 = ep[j + 3];
    acc = fmaf(__int_as_float(e0.y), a[(size_t)e0.x * 64 + lane], acc);
    acc = fmaf(__int_as_float(e1.y), a[(size_t)e1.x * 64 + lane], acc);
    acc = fmaf(__int_as_float(e2.y), a[(size_t)e2.x * 64 + lane], acc);
    acc = fmaf(__int_as_float(e3.y), a[(size_t)e3.x * 64 + lane], acc);
  }
  for (; j < ecnt; ++j) {
    int2 e = ep[j];
    acc = fmaf(__int_as_float(e.y), a[(size_t)e.x * 64 + lane], acc);
  }
  h[(size_t)wid * 64 + lane] = fmaxf(acc, 0.f);
}

// ---------------------------------------------------------------------------
// fused mean-pool (sorted batch, binary search) + lin1+relu + lin2, wave/graph
__global__ __launch_bounds__(256) void head_kernel(
    const float* __restrict__ h, const int* __restrict__ batch,
    const float* __restrict__ l1w, const float* __restrict__ l1b,
    const float* __restrict__ l2w, const float* __restrict__ l2b,
    float* __restrict__ out)
{
  int g = (blockIdx.x * 256 + threadIdx.x) >> 6;
  int lane = threadIdx.x & 63;
  if (g >= N_GRAPHS) return;
  int lo = 0, hi = N_NODES;
  while (lo < hi) { int mid = (lo + hi) >> 1; if (batch[mid] < g) lo = mid + 1; else hi = mid; }
  int start = lo;
  hi = N_NODES;
  while (lo < hi) { int mid = (lo + hi) >> 1; if (batch[mid] < g + 1) lo = mid + 1; else hi = mid; }
  int end = lo;

  float sum = 0.f;
  for (int v = start; v < end; ++v) sum += h[(size_t)v * 64 + lane];
  float cntf = (float)(end - start);
  float gx = sum / fmaxf(cntf, 1.f);

  float acc = l1b[lane];
  for (int k = 0; k < 64; ++k) {
    float gxk = __shfl(gx, k);
    acc = fmaf(gxk, l1w[k * 64 + lane], acc);
  }
  float t = fmaxf(acc, 0.f);
  float p0 = t * l2w[lane * 3 + 0];
  float p1 = t * l2w[lane * 3 + 1];
  float p2 = t * l2w[lane * 3 + 2];
  for (int off = 32; off > 0; off >>= 1) {
    p0 += __shfl_down(p0, off);
    p1 += __shfl_down(p1, off);
    p2 += __shfl_down(p2, off);
  }
  if (lane == 0) {
    out[g * 3 + 0] = p0 + l2b[0];
    out[g * 3 + 1] = p1 + l2b[1];
    out[g * 3 + 2] = p2 + l2b[2];
  }
}

// ---------------------------------------------------------------------------
extern "C" void kernel_launch(void* const* d_in, const int* in_sizes, int n_in,
                              void* d_out, int out_size, void* d_ws, size_t ws_size,
                              hipStream_t stream)
{
  (void)in_sizes; (void)n_in; (void)out_size; (void)ws_size;
  const float* x     = (const float*)d_in[0];
  const int*   ei    = (const int*)d_in[1];
  const float* ea    = (const float*)d_in[2];
  const int*   batch = (const int*)d_in[3];
  const float* emb_w = (const float*)d_in[4];
  const float* emb_b = (const float*)d_in[5];
  const float* cw1   = (const float*)d_in[6];
  const float* cb1   = (const float*)d_in[7];
  const float* cw2   = (const float*)d_in[8];
  const float* cw3   = (const float*)d_in[9];
  const float* cb3   = (const float*)d_in[10];
  const float* l1w   = (const float*)d_in[11];
  const float* l1b   = (const float*)d_in[12];
  const float* l2w   = (const float*)d_in[13];
  const float* l2b   = (const float*)d_in[14];
  float* out = (float*)d_out;

  char* wsb = (char*)d_ws;
  size_t off = 0;
  auto alloc = [&](size_t bytes) {
    char* p = wsb + off;
    off = (off + bytes + 255) & ~(size_t)255;
    return p;
  };
  float* h       = (float*)alloc(sizeof(float) * (size_t)N_NODES * 64);
  float* a_buf   = (float*)alloc(sizeof(float) * (size_t)N_NODES * 64);
  float* cc_buf  = (float*)alloc(sizeof(float) * (size_t)N_NODES * 64);
  int2*  csr     = (int2*)alloc(sizeof(int2) * (size_t)N_EDGES);
  int*   row_off = (int*)alloc(sizeof(int) * (N_NODES + 1));
  unsigned long long* packed = (unsigned long long*)alloc(sizeof(unsigned long long) * N_NODES);
  float* degw    = (float*)alloc(sizeof(float) * N_NODES);
  int*   bsum    = (int*)alloc(sizeof(int) * 512);
  int*   bpre    = (int*)alloc(sizeof(int) * 512);
  // rank is only live between hist and scatter, both before any matvec writes
  // a_buf -> alias it onto a_buf (12.8 MB < 25.6 MB), saving workspace.
  int* rank = (int*)a_buf;

  (void)hipMemsetAsync(packed, 0, sizeof(unsigned long long) * N_NODES, stream);

  embed_kernel<<<(N_NODES * 64 + 255) / 256, 256, 0, stream>>>(x, emb_w, emb_b, h);
  hist_kernel<<<(N_EDGES + 255) / 256, 256, 0, stream>>>(ei, ea, packed, rank);
  int nb = (N_NODES + 255) / 256;  // 391
  scan1_kernel<<<nb, 256, 0, stream>>>(packed, row_off, bsum);
  scan2_kernel<<<1, 512, 0, stream>>>(bsum, bpre, nb);
  scan3_kernel<<<(N_NODES + 1 + 255) / 256, 256, 0, stream>>>(row_off, bpre, packed, degw);
  scatter_kernel<<<(N_EDGES + 255) / 256, 256, 0, stream>>>(ei, ea, row_off, rank, csr);

  for (int l = 0; l < NLAYER; ++l) {
    matvec3_kernel<<<(N_NODES + 511) / 512, 256, 0, stream>>>(
        h, cw1 + l * 4096, cb1 + l * 64, cw2 + l * 4096, cw3 + l * 4096,
        cb3 + l * 64, degw, a_buf, cc_buf);
    agg_kernel<<<(N_NODES * 64 + 255) / 256, 256, 0, stream>>>(
        a_buf, cc_buf, row_off, csr, h);
  }

  head_kernel<<<(N_GRAPHS * 64 + 255) / 256, 256, 0, stream>>>(
      h, batch, l1w, l1b, l2w, l2b, out);
}